// Round 1
// baseline (1306.043 us; speedup 1.0000x reference)
//
#include <hip/hip_runtime.h>

#define N_NODES 100000
#define NEDGE   1600000
#define D       32

// One edge is handled by 8 consecutive threads; each thread owns a float4
// slice (4 features) of the 32-wide feature row. Lanes 0..7 of a group read
// a contiguous 128B row of x (coalesced within the group), then scatter with
// 4 float atomicAdds to the destination row.
__global__ void spmm_scatter_kernel(const int* __restrict__ src,
                                    const int* __restrict__ dst,
                                    const float* __restrict__ w,
                                    const float* __restrict__ x,
                                    float* __restrict__ out) {
    long gid = (long)blockIdx.x * blockDim.x + threadIdx.x;
    const long total = (long)NEDGE * 8;
    if (gid >= total) return;
    int e = (int)(gid >> 3);
    int c = (int)(gid & 7);
    int s = src[e];
    int d = dst[e];
    float wt = w[e];
    const float4 xv = *reinterpret_cast<const float4*>(&x[(long)s * D + c * 4]);
    float* o = &out[(long)d * D + c * 4];
    atomicAdd(o + 0, wt * xv.x);
    atomicAdd(o + 1, wt * xv.y);
    atomicAdd(o + 2, wt * xv.z);
    atomicAdd(o + 3, wt * xv.w);
}

extern "C" void kernel_launch(void* const* d_in, const int* in_sizes, int n_in,
                              void* d_out, int out_size, void* d_ws, size_t ws_size,
                              hipStream_t stream) {
    const float* x    = (const float*)d_in[0];
    const int*   esrc = (const int*)d_in[1];
    const int*   edst = (const int*)d_in[2];
    const float* ew   = (const float*)d_in[3];
    float* out = (float*)d_out;
    float* y   = (float*)d_ws;   // intermediate A·x, 12.8 MB

    const size_t nbytes = (size_t)N_NODES * D * sizeof(float);
    hipMemsetAsync(y,   0, nbytes, stream);
    hipMemsetAsync(out, 0, nbytes, stream);

    const int  threads = 256;
    const long total   = (long)NEDGE * 8;
    const int  blocks  = (int)((total + threads - 1) / threads);

    spmm_scatter_kernel<<<blocks, threads, 0, stream>>>(esrc, edst, ew, x, y);
    spmm_scatter_kernel<<<blocks, threads, 0, stream>>>(esrc, edst, ew, y, out);
}

// Round 2
// 272.046 us; speedup vs baseline: 4.8008x; 4.8008x over previous
//
#include <hip/hip_runtime.h>

#define N_NODES 100000
#define NEDGE   1600000
#define D       32
#define SCAN_B  256
#define NBLK_SCAN ((N_NODES + SCAN_B - 1) / SCAN_B)   // 391

// ---------- CSR build ----------

__global__ void hist_kernel(const int* __restrict__ dst, int* __restrict__ deg) {
    int e = blockIdx.x * blockDim.x + threadIdx.x;
    if (e < NEDGE) atomicAdd(&deg[dst[e]], 1);
}

__global__ void scan1_kernel(const int* __restrict__ deg, int* __restrict__ off,
                             int* __restrict__ part) {
    __shared__ int s[SCAN_B];
    int i = blockIdx.x * SCAN_B + threadIdx.x;
    int v = (i < N_NODES) ? deg[i] : 0;
    s[threadIdx.x] = v;
    __syncthreads();
    for (int o = 1; o < SCAN_B; o <<= 1) {
        int t = (threadIdx.x >= o) ? s[threadIdx.x - o] : 0;
        __syncthreads();
        s[threadIdx.x] += t;
        __syncthreads();
    }
    if (i < N_NODES) off[i] = s[threadIdx.x] - v;          // exclusive within block
    if (threadIdx.x == SCAN_B - 1) part[blockIdx.x] = s[SCAN_B - 1];
}

__global__ void scan2_kernel(int* part) {                  // single block of 512
    __shared__ int s[512];
    int v = (threadIdx.x < NBLK_SCAN) ? part[threadIdx.x] : 0;
    s[threadIdx.x] = v;
    __syncthreads();
    for (int o = 1; o < 512; o <<= 1) {
        int t = (threadIdx.x >= o) ? s[threadIdx.x - o] : 0;
        __syncthreads();
        s[threadIdx.x] += t;
        __syncthreads();
    }
    if (threadIdx.x < NBLK_SCAN) part[threadIdx.x] = s[threadIdx.x] - v;  // exclusive
}

__global__ void scan3_kernel(int* __restrict__ off, const int* __restrict__ part) {
    int i = blockIdx.x * SCAN_B + threadIdx.x;
    if (i < N_NODES) off[i] += part[blockIdx.x];
}

__global__ void fill_kernel(const int* __restrict__ src, const int* __restrict__ dst,
                            const float* __restrict__ w, const int* __restrict__ off,
                            int* __restrict__ cur, int* __restrict__ csr_src,
                            float* __restrict__ csr_w) {
    int e = blockIdx.x * blockDim.x + threadIdx.x;
    if (e >= NEDGE) return;
    int d = dst[e];
    int slot = off[d] + atomicAdd(&cur[d], 1);
    csr_src[slot] = src[e];
    csr_w[slot]   = w[e];
}

// ---------- gather SpMM (no atomics) ----------
// 8 threads per node; each owns a float4 slice of the 32-wide feature row.
__global__ void spmm_gather_kernel(const int* __restrict__ off, const int* __restrict__ deg,
                                   const int* __restrict__ csr_src, const float* __restrict__ csr_w,
                                   const float* __restrict__ x, float* __restrict__ out) {
    int gid = blockIdx.x * blockDim.x + threadIdx.x;
    if (gid >= N_NODES * 8) return;
    int node = gid >> 3;
    int c    = gid & 7;
    int start = off[node];
    int len   = deg[node];
    float4 acc = {0.f, 0.f, 0.f, 0.f};
    for (int k = 0; k < len; ++k) {
        int   s  = csr_src[start + k];
        float wt = csr_w[start + k];
        const float4 xv = *reinterpret_cast<const float4*>(&x[(long)s * D + c * 4]);
        acc.x += wt * xv.x;
        acc.y += wt * xv.y;
        acc.z += wt * xv.z;
        acc.w += wt * xv.w;
    }
    *reinterpret_cast<float4*>(&out[(long)node * D + c * 4]) = acc;
}

// ---------- fallback (round-1 atomic scatter) if ws too small ----------
__global__ void spmm_scatter_kernel(const int* __restrict__ src, const int* __restrict__ dst,
                                    const float* __restrict__ w, const float* __restrict__ x,
                                    float* __restrict__ out) {
    long gid = (long)blockIdx.x * blockDim.x + threadIdx.x;
    if (gid >= (long)NEDGE * 8) return;
    int e = (int)(gid >> 3);
    int c = (int)(gid & 7);
    int s = src[e], d = dst[e];
    float wt = w[e];
    const float4 xv = *reinterpret_cast<const float4*>(&x[(long)s * D + c * 4]);
    float* o = &out[(long)d * D + c * 4];
    atomicAdd(o + 0, wt * xv.x);
    atomicAdd(o + 1, wt * xv.y);
    atomicAdd(o + 2, wt * xv.z);
    atomicAdd(o + 3, wt * xv.w);
}

extern "C" void kernel_launch(void* const* d_in, const int* in_sizes, int n_in,
                              void* d_out, int out_size, void* d_ws, size_t ws_size,
                              hipStream_t stream) {
    const float* x    = (const float*)d_in[0];
    const int*   esrc = (const int*)d_in[1];
    const int*   edst = (const int*)d_in[2];
    const float* ew   = (const float*)d_in[3];
    float* out = (float*)d_out;

    char* ws = (char*)d_ws;
    const size_t y_bytes    = (size_t)N_NODES * D * sizeof(float);   // 12.8 MB
    const size_t n_ints     = (size_t)N_NODES * sizeof(int);         // 400 KB
    const size_t part_bytes = 512 * sizeof(int);
    const size_t e_ints     = (size_t)NEDGE * sizeof(int);           // 6.4 MB

    size_t o = 0;
    float* y       = (float*)(ws + o); o += y_bytes;
    int*   deg     = (int*)  (ws + o); o += n_ints;
    int*   off     = (int*)  (ws + o); o += n_ints;
    int*   cur     = (int*)  (ws + o); o += n_ints;
    int*   part    = (int*)  (ws + o); o += part_bytes;
    int*   csr_src = (int*)  (ws + o); o += e_ints;
    float* csr_w   = (float*)(ws + o); o += e_ints;

    if (ws_size < o) {
        // Fallback: atomic scatter (needs only y)
        hipMemsetAsync(y, 0, y_bytes, stream);
        hipMemsetAsync(out, 0, y_bytes, stream);
        const long total = (long)NEDGE * 8;
        const int blocks = (int)((total + 255) / 256);
        spmm_scatter_kernel<<<blocks, 256, 0, stream>>>(esrc, edst, ew, x, y);
        spmm_scatter_kernel<<<blocks, 256, 0, stream>>>(esrc, edst, ew, y, out);
        return;
    }

    hipMemsetAsync(deg, 0, n_ints, stream);
    hipMemsetAsync(cur, 0, n_ints, stream);

    const int eblocks = (NEDGE + 255) / 256;
    hist_kernel<<<eblocks, 256, 0, stream>>>(edst, deg);
    scan1_kernel<<<NBLK_SCAN, SCAN_B, 0, stream>>>(deg, off, part);
    scan2_kernel<<<1, 512, 0, stream>>>(part);
    scan3_kernel<<<NBLK_SCAN, SCAN_B, 0, stream>>>(off, part);
    fill_kernel<<<eblocks, 256, 0, stream>>>(esrc, edst, ew, off, cur, csr_src, csr_w);

    const int gthreads = N_NODES * 8;
    const int gblocks  = (gthreads + 255) / 256;
    spmm_gather_kernel<<<gblocks, 256, 0, stream>>>(off, deg, csr_src, csr_w, x, y);
    spmm_gather_kernel<<<gblocks, 256, 0, stream>>>(off, deg, csr_src, csr_w, y, out);
}